// Round 8
// baseline (403.551 us; speedup 1.0000x reference)
//
#include <hip/hip_runtime.h>
#include <stdint.h>

#define HID 64
#define INDIM 128
#define CSREP 32       // colsum atomic replicas (breaks same-line contention)

typedef __attribute__((ext_vector_type(8))) short bf16x8;
typedef __attribute__((ext_vector_type(4))) float f32x4;
typedef __attribute__((ext_vector_type(2))) float f32x2;

__host__ __device__ __forceinline__ void tf2x32(uint32_t k0, uint32_t k1,
                                                uint32_t x0, uint32_t x1,
                                                uint32_t& o0, uint32_t& o1) {
  uint32_t ks2 = k0 ^ k1 ^ 0x1BD11BDAu;
#define ROTL(v, r) (((v) << (r)) | ((v) >> (32 - (r))))
#define RND(r) { x0 += x1; x1 = ROTL(x1, r); x1 ^= x0; }
  x0 += k0; x1 += k1;
  RND(13) RND(15) RND(26) RND(6)
  x0 += k1; x1 += ks2 + 1u;
  RND(17) RND(29) RND(16) RND(24)
  x0 += ks2; x1 += k0 + 2u;
  RND(13) RND(15) RND(26) RND(6)
  x0 += k0; x1 += k1 + 3u;
  RND(17) RND(29) RND(16) RND(24)
  x0 += k1; x1 += ks2 + 4u;
  RND(13) RND(15) RND(26) RND(6)
  x0 += ks2; x1 += k0 + 5u;
  o0 = x0; o1 = x1;
#undef RND
#undef ROTL
}

__device__ __forceinline__ float tf_uniform(uint32_t ka, uint32_t kb, uint32_t j) {
  uint32_t o0, o1;
  tf2x32(ka, kb, 0u, j, o0, o1);
  uint32_t bits = o0 ^ o1;
  uint32_t f = (bits >> 9) | 0x3f800000u;
  return __uint_as_float(f) - 1.0f;
}

__device__ __forceinline__ unsigned short f2bf(float f) {
  uint32_t x = __float_as_uint(f);
  uint32_t r = (x + 0x7fffu + ((x >> 16) & 1u)) >> 16;   // RNE
  return (unsigned short)r;
}

__device__ __forceinline__ float bf2f_lo(uint32_t u) { return __uint_as_float(u << 16); }
__device__ __forceinline__ float bf2f_hi(uint32_t u) { return __uint_as_float(u & 0xffff0000u); }

__device__ __forceinline__ unsigned char f2fp8(float v) {
  return (unsigned char)(__builtin_amdgcn_cvt_pk_fp8_f32(v, 0.f, 0, false) & 0xff);
}

// K1: degree histogram via global atomics (CSR edge order is numerically
// irrelevant: f32 sums of fp8/bf16 inputs are exact -> order-independent).
// Prologue absorbs wcvt (w1t/w2t transpose-convert, colsumR zero).
__global__ __launch_bounds__(256) void hist_k(const int* __restrict__ dst,
                                              int* __restrict__ deg,
                                              const float* __restrict__ w1,
                                              const float* __restrict__ w2,
                                              unsigned short* __restrict__ w1t,
                                              unsigned short* __restrict__ w2t,
                                              float* __restrict__ colsumR, int E) {
  int i = blockIdx.x * 256 + threadIdx.x;
  if (i < CSREP * HID) colsumR[i] = 0.f;
  if (i < INDIM * HID) {
    int c = i >> 7, k = i & 127;
    w1t[i] = f2bf(w1[k * HID + c]);
  } else if (i < INDIM * HID + HID * HID) {
    int j = i - INDIM * HID;
    int c = j >> 6, k = j & 63;
    w2t[j] = f2bf(w2[k * HID + c]);
  }
  if (i < E) atomicAdd(&deg[dst[i]], 1);
}

// K2a: per-block inclusive scan of deg (256 nodes/block) -> scn, block totals.
__global__ __launch_bounds__(256) void scan1_k(const int* __restrict__ deg,
                                               int* __restrict__ scn,
                                               int* __restrict__ btot, int n) {
  __shared__ int sa[256], sb[256];
  int b = blockIdx.x, t = threadIdx.x;
  int node = b * 256 + t;
  int v = (node < n) ? deg[node] : 0;
  sa[t] = v;
  __syncthreads();
  int* cur = sa; int* nxt = sb;
  for (int off = 1; off < 256; off <<= 1) {
    int x = cur[t] + ((t >= off) ? cur[t - off] : 0);
    __syncthreads();
    nxt[t] = x;
    __syncthreads();
    int* tmp = cur; cur = nxt; nxt = tmp;
  }
  if (node < n) scn[node] = cur[t];
  if (t == 255) btot[b] = cur[255];
}

// K2b: add block-prefix; emit rowstart, cursor (scatter write heads), norm.
__global__ __launch_bounds__(256) void scan2_k(const int* __restrict__ scn,
                                               const int* __restrict__ btot,
                                               const int* __restrict__ deg,
                                               int* __restrict__ rowstart,
                                               int* __restrict__ cursor,
                                               float* __restrict__ norm,
                                               int n, int E) {
  __shared__ int red[256];
  int b = blockIdx.x, t = threadIdx.x;
  int acc = 0;
  for (int i = t; i < b; i += 256) acc += btot[i];
  red[t] = acc;
  __syncthreads();
  for (int off = 128; off > 0; off >>= 1) {
    if (t < off) red[t] += red[t + off];
    __syncthreads();
  }
  int off0 = red[0];
  int node = b * 256 + t;
  if (node < n) {
    int cnt = deg[node];
    int rs = off0 + scn[node] - cnt;
    rowstart[node] = rs;
    cursor[node] = rs;
    norm[node] = rsqrtf((float)(cnt + 1));
  }
  if (b == 0 && t == 0) rowstart[n] = E;
}

// K2c: scatter edges into CSR slots (order within a row nondeterministic — safe).
__global__ __launch_bounds__(256) void scat_k(const int* __restrict__ src,
                                              const int* __restrict__ dst,
                                              int* __restrict__ cursor,
                                              int* __restrict__ csr, int E) {
  int i = blockIdx.x * 256 + threadIdx.x;
  if (i < E) {
    int d = dst[i], s = src[i];
    int pos = atomicAdd(&cursor[d], 1);
    csr[pos] = s;
  }
}

// MFMA gemm1: h0 = fp8(norm * (feat @ w1)). One wave per 16-node strip.
__global__ __launch_bounds__(256) void gemm1(const float* __restrict__ feat,
                                             const unsigned short* __restrict__ w1t,
                                             const float* __restrict__ norm,
                                             unsigned char* __restrict__ h0, int n) {
  int t = threadIdx.x;
  int wv = t >> 6, lane = t & 63;
  int strip = blockIdx.x * 4 + wv;
  if (strip * 16 >= n) return;
  int m = lane & 15, q = lane >> 4;
  bf16x8 Bf[4][4];
#pragma unroll
  for (int kc = 0; kc < 4; kc++)
#pragma unroll
    for (int ct = 0; ct < 4; ct++)
      Bf[kc][ct] = *(const bf16x8*)(w1t + (ct * 16 + m) * INDIM + kc * 32 + q * 8);
  const float* arow = feat + (size_t)(strip * 16 + m) * INDIM;
  bf16x8 Af[4];
#pragma unroll
  for (int kc = 0; kc < 4; kc++) {
    const float* pa = arow + kc * 32 + q * 8;
    bf16x8 a;
#pragma unroll
    for (int j = 0; j < 8; j++) a[j] = (short)f2bf(pa[j]);
    Af[kc] = a;
  }
  f32x4 acc[4] = {{0.f,0.f,0.f,0.f},{0.f,0.f,0.f,0.f},{0.f,0.f,0.f,0.f},{0.f,0.f,0.f,0.f}};
#pragma unroll
  for (int kc = 0; kc < 4; kc++)
#pragma unroll
    for (int ct = 0; ct < 4; ct++)
      acc[ct] = __builtin_amdgcn_mfma_f32_16x16x32_bf16(Af[kc], Bf[kc][ct], acc[ct], 0, 0, 0);
#pragma unroll
  for (int r = 0; r < 4; r++) {
    int row = strip * 16 + q * 4 + r;
    float nm = norm[row];
#pragma unroll
    for (int ct = 0; ct < 4; ct++)
      h0[(size_t)row * HID + ct * 16 + m] = f2fp8(acc[ct][r] * nm);
  }
}

// 4-node-per-wave CSR gather over fp8 rows, MODE 0 only:
// fused relu/dropout(ballot)/prescale -> fp8 out.
__global__ __launch_bounds__(256) void gather_k(const uint32_t* __restrict__ h8,
                                                uint32_t* __restrict__ outp,
                                                const int* __restrict__ rowstart,
                                                const int* __restrict__ csr,
                                                const float* __restrict__ norm,
                                                int n, uint32_t ka, uint32_t kb) {
  int wid = (int)((blockIdx.x * 256u + threadIdx.x) >> 6);
  int d0 = wid * 4;
  if (d0 >= n) return;
  int lane = threadIdx.x & 63;
  int g = lane >> 4, c4 = lane & 15;
  int g4 = g << 2;

  int rr = d0 + (lane < 4 ? lane : 4);
  if (rr > n) rr = n;
  int rsl = rowstart[rr];
  int r0[5];
#pragma unroll
  for (int i = 0; i < 5; ++i) r0[i] = __shfl(rsl, i);
  int L[4];
#pragma unroll
  for (int i = 0; i < 4; ++i) L[i] = r0[i + 1] - r0[i];

  int selfrow = d0 + g; if (selfrow >= n) selfrow = d0;
  uint32_t uself = h8[(size_t)selfrow * 16 + c4];

  int idx[4];
#pragma unroll
  for (int i = 0; i < 4; ++i) {
    int la = L[i] < 32 ? L[i] : 32;
    idx[i] = (lane < la) ? csr[r0[i] + lane] : 0;
  }

  uint32_t u[4][8];
#pragma unroll
  for (int i = 0; i < 4; ++i) {
#pragma unroll
    for (int t = 0; t < 8; ++t) {
      int s = __builtin_amdgcn_ds_bpermute(16 * t + g4, idx[i]);
      u[i][t] = (4 * t + g < L[i]) ? h8[(size_t)(uint32_t)s * 16 + c4] : 0u;
    }
  }

  f32x2 al[4], ah[4];
#pragma unroll
  for (int i = 0; i < 4; ++i) { al[i] = (f32x2){0.f, 0.f}; ah[i] = (f32x2){0.f, 0.f}; }
#pragma unroll
  for (int i = 0; i < 4; ++i) {
#pragma unroll
    for (int t = 0; t < 8; ++t) {
      al[i] += __builtin_amdgcn_cvt_pk_f32_fp8((int)u[i][t], false);
      ah[i] += __builtin_amdgcn_cvt_pk_f32_fp8((int)u[i][t], true);
    }
  }

#pragma unroll
  for (int i = 0; i < 4; ++i) {
    if (L[i] > 32) {
      for (int e0 = 32; e0 < L[i]; e0 += 4) {
        int e = e0 + g;
        uint32_t uu = 0u;
        if (e < L[i]) {
          int s = csr[r0[i] + e];
          uu = h8[(size_t)(uint32_t)s * 16 + c4];
        }
        al[i] += __builtin_amdgcn_cvt_pk_f32_fp8((int)uu, false);
        ah[i] += __builtin_amdgcn_cvt_pk_f32_fp8((int)uu, true);
      }
    }
  }

  f32x2 sl, sh, rl2, rh2;
  sl = (g & 1) ? al[0] : al[1];
  sh = (g & 1) ? ah[0] : ah[1];
  rl2.x = __shfl_xor(sl.x, 16); rl2.y = __shfl_xor(sl.y, 16);
  rh2.x = __shfl_xor(sh.x, 16); rh2.y = __shfl_xor(sh.y, 16);
  f32x2 fABl = ((g & 1) ? al[1] : al[0]) + rl2;
  f32x2 fABh = ((g & 1) ? ah[1] : ah[0]) + rh2;
  sl = (g & 1) ? al[2] : al[3];
  sh = (g & 1) ? ah[2] : ah[3];
  rl2.x = __shfl_xor(sl.x, 16); rl2.y = __shfl_xor(sl.y, 16);
  rh2.x = __shfl_xor(sh.x, 16); rh2.y = __shfl_xor(sh.y, 16);
  f32x2 fCDl = ((g & 1) ? al[3] : al[2]) + rl2;
  f32x2 fCDh = ((g & 1) ? ah[3] : ah[2]) + rh2;
  sl = (g & 2) ? fABl : fCDl;
  sh = (g & 2) ? fABh : fCDh;
  rl2.x = __shfl_xor(sl.x, 32); rl2.y = __shfl_xor(sl.y, 32);
  rh2.x = __shfl_xor(sh.x, 32); rh2.y = __shfl_xor(sh.y, 32);
  f32x2 tl = ((g & 2) ? fCDl : fABl) + rl2;
  f32x2 th = ((g & 2) ? fCDh : fABh) + rh2;

  tl += __builtin_amdgcn_cvt_pk_f32_fp8((int)uself, false);
  th += __builtin_amdgcn_cvt_pk_f32_fp8((int)uself, true);

  int d = d0 + g;
  uint32_t jb = (uint32_t)d0 * 64u + (uint32_t)lane;
  float u0 = tf_uniform(ka, kb, jb);
  float u1 = tf_uniform(ka, kb, jb + 64u);
  float u2 = tf_uniform(ka, kb, jb + 128u);
  float u3 = tf_uniform(ka, kb, jb + 192u);
  unsigned long long kp0 = __ballot(u0 < 0.5f);
  unsigned long long kp1 = __ballot(u1 < 0.5f);
  unsigned long long kp2 = __ballot(u2 < 0.5f);
  unsigned long long kp3 = __ballot(u3 < 0.5f);
  unsigned long long keep = (g & 2) ? ((g & 1) ? kp3 : kp2)
                                    : ((g & 1) ? kp1 : kp0);
  uint32_t kb4 = (uint32_t)(keep >> (4 * c4)) & 15u;
  float nm = norm[d < n ? d : d0];
  float v0 = fmaxf(tl.x * nm, 0.f), v1 = fmaxf(tl.y * nm, 0.f);
  float v2 = fmaxf(th.x * nm, 0.f), v3 = fmaxf(th.y * nm, 0.f);
  float s2 = 2.f * nm;
  v0 = (kb4 & 1u) ? v0 * s2 : 0.f;
  v1 = (kb4 & 2u) ? v1 * s2 : 0.f;
  v2 = (kb4 & 4u) ? v2 * s2 : 0.f;
  v3 = (kb4 & 8u) ? v3 * s2 : 0.f;
  if (d < n) {
    int o = __builtin_amdgcn_cvt_pk_fp8_f32(v0, v1, 0, false);
    o = __builtin_amdgcn_cvt_pk_fp8_f32(v2, v3, o, true);
    outp[(size_t)d * 16 + c4] = (uint32_t)o;
  }
}

// Fused gather<1> + gemm2: block = one 16-node strip (4 waves x 4 nodes).
__global__ __launch_bounds__(256) void gather2gemm2_k(
    const uint32_t* __restrict__ h8, const int* __restrict__ rowstart,
    const int* __restrict__ csr, const float* __restrict__ norm,
    const unsigned short* __restrict__ w2t, unsigned short* __restrict__ h2,
    float* __restrict__ colsumR, int n, uint32_t ka, uint32_t kb) {
  __shared__ unsigned short abuf[16][72];   // +8 pad breaks bank conflicts
  int t = threadIdx.x;
  int wv = t >> 6, lane = t & 63;
  int node0 = blockIdx.x * 16;
  int d0 = node0 + wv * 4;
  int g = lane >> 4, c4 = lane & 15;
  int g4 = g << 2;
  int lrow = (wv << 2) + g;

  if (d0 < n) {
    int rr = d0 + (lane < 4 ? lane : 4);
    if (rr > n) rr = n;
    int rsl = rowstart[rr];
    int r0[5];
#pragma unroll
    for (int i = 0; i < 5; ++i) r0[i] = __shfl(rsl, i);
    int L[4];
#pragma unroll
    for (int i = 0; i < 4; ++i) L[i] = r0[i + 1] - r0[i];

    int selfrow = d0 + g; if (selfrow >= n) selfrow = d0;
    uint32_t uself = h8[(size_t)selfrow * 16 + c4];

    int idx[4];
#pragma unroll
    for (int i = 0; i < 4; ++i) {
      int la = L[i] < 32 ? L[i] : 32;
      idx[i] = (lane < la) ? csr[r0[i] + lane] : 0;
    }

    uint32_t u[4][8];
#pragma unroll
    for (int i = 0; i < 4; ++i) {
#pragma unroll
      for (int tt = 0; tt < 8; ++tt) {
        int s = __builtin_amdgcn_ds_bpermute(16 * tt + g4, idx[i]);
        u[i][tt] = (4 * tt + g < L[i]) ? h8[(size_t)(uint32_t)s * 16 + c4] : 0u;
      }
    }

    f32x2 al[4], ah[4];
#pragma unroll
    for (int i = 0; i < 4; ++i) { al[i] = (f32x2){0.f, 0.f}; ah[i] = (f32x2){0.f, 0.f}; }
#pragma unroll
    for (int i = 0; i < 4; ++i) {
#pragma unroll
      for (int tt = 0; tt < 8; ++tt) {
        al[i] += __builtin_amdgcn_cvt_pk_f32_fp8((int)u[i][tt], false);
        ah[i] += __builtin_amdgcn_cvt_pk_f32_fp8((int)u[i][tt], true);
      }
    }

#pragma unroll
    for (int i = 0; i < 4; ++i) {
      if (L[i] > 32) {
        for (int e0 = 32; e0 < L[i]; e0 += 4) {
          int e = e0 + g;
          uint32_t uu = 0u;
          if (e < L[i]) {
            int s = csr[r0[i] + e];
            uu = h8[(size_t)(uint32_t)s * 16 + c4];
          }
          al[i] += __builtin_amdgcn_cvt_pk_f32_fp8((int)uu, false);
          ah[i] += __builtin_amdgcn_cvt_pk_f32_fp8((int)uu, true);
        }
      }
    }

    f32x2 sl, sh, rl2, rh2;
    sl = (g & 1) ? al[0] : al[1];
    sh = (g & 1) ? ah[0] : ah[1];
    rl2.x = __shfl_xor(sl.x, 16); rl2.y = __shfl_xor(sl.y, 16);
    rh2.x = __shfl_xor(sh.x, 16); rh2.y = __shfl_xor(sh.y, 16);
    f32x2 fABl = ((g & 1) ? al[1] : al[0]) + rl2;
    f32x2 fABh = ((g & 1) ? ah[1] : ah[0]) + rh2;
    sl = (g & 1) ? al[2] : al[3];
    sh = (g & 1) ? ah[2] : ah[3];
    rl2.x = __shfl_xor(sl.x, 16); rl2.y = __shfl_xor(sl.y, 16);
    rh2.x = __shfl_xor(sh.x, 16); rh2.y = __shfl_xor(sh.y, 16);
    f32x2 fCDl = ((g & 1) ? al[3] : al[2]) + rl2;
    f32x2 fCDh = ((g & 1) ? ah[3] : ah[2]) + rh2;
    sl = (g & 2) ? fABl : fCDl;
    sh = (g & 2) ? fABh : fCDh;
    rl2.x = __shfl_xor(sl.x, 32); rl2.y = __shfl_xor(sl.y, 32);
    rh2.x = __shfl_xor(sh.x, 32); rh2.y = __shfl_xor(sh.y, 32);
    f32x2 tl = ((g & 2) ? fCDl : fABl) + rl2;
    f32x2 th = ((g & 2) ? fCDh : fABh) + rh2;

    tl += __builtin_amdgcn_cvt_pk_f32_fp8((int)uself, false);
    th += __builtin_amdgcn_cvt_pk_f32_fp8((int)uself, true);

    uint2 w;
    w.x = (uint32_t)f2bf(tl.x) | ((uint32_t)f2bf(tl.y) << 16);
    w.y = (uint32_t)f2bf(th.x) | ((uint32_t)f2bf(th.y) << 16);
    if (d0 + g >= n) { w.x = 0u; w.y = 0u; }
    *(uint2*)&abuf[lrow][4 * c4] = w;
  } else {
    uint2 z; z.x = 0u; z.y = 0u;
    *(uint2*)&abuf[lrow][4 * c4] = z;
  }
  __syncthreads();
  if (wv != 0) return;
  if (node0 >= n) return;

  int m = lane & 15, q = lane >> 4;
  f32x4 acc[4] = {{0.f,0.f,0.f,0.f},{0.f,0.f,0.f,0.f},{0.f,0.f,0.f,0.f},{0.f,0.f,0.f,0.f}};
#pragma unroll
  for (int kc = 0; kc < 2; kc++) {
    bf16x8 Af = *(const bf16x8*)&abuf[m][kc * 32 + q * 8];
#pragma unroll
    for (int ct = 0; ct < 4; ct++) {
      bf16x8 Bf = *(const bf16x8*)(w2t + (ct * 16 + m) * HID + kc * 32 + q * 8);
      acc[ct] = __builtin_amdgcn_mfma_f32_16x16x32_bf16(Af, Bf, acc[ct], 0, 0, 0);
    }
  }
  float cs[4] = {0.f, 0.f, 0.f, 0.f};
#pragma unroll
  for (int r = 0; r < 4; r++) {
    int row = node0 + q * 4 + r;
    if (row < n) {
      float nm = norm[row];
#pragma unroll
      for (int ct = 0; ct < 4; ct++) {
        int col = ct * 16 + m;
        float v = fmaxf(acc[ct][r] * nm, 0.f);
        float uu = tf_uniform(ka, kb, (uint32_t)row * 64u + (uint32_t)col);
        v = (uu < 0.5f) ? v * 2.f : 0.f;
        h2[(size_t)row * HID + col] = f2bf(v);
        cs[ct] += v;
      }
    }
  }
#pragma unroll
  for (int ct = 0; ct < 4; ct++) {
    cs[ct] += __shfl_xor(cs[ct], 16);
    cs[ct] += __shfl_xor(cs[ct], 32);
  }
  if (q == 0) {
    float* dstc = colsumR + (blockIdx.x & (CSREP - 1)) * HID;
#pragma unroll
    for (int ct = 0; ct < 4; ct++) atomicAdd(&dstc[ct * 16 + m], cs[ct]);
  }
}

__global__ __launch_bounds__(128) void final_k(const uint32_t* __restrict__ h2u,
                                               const float* __restrict__ colsumR,
                                               const float* __restrict__ conv_w,
                                               const float* __restrict__ conv_b,
                                               const float* __restrict__ ref_radius,
                                               float* __restrict__ out, int n) {
  __shared__ float rows[128 * 67];
  __shared__ float omean[124];
  __shared__ float cm[HID];
  int t = threadIdx.x;
  int node0 = blockIdx.x * 128;
  if (t < HID) {
    float s = 0.f;
#pragma unroll
    for (int r = 0; r < CSREP; r++) s += colsumR[r * HID + t];
    cm[t] = s * (1.0f / (float)n);
  }
  for (int idx = t; idx < 128 * 32; idx += 128) {
    int r = idx >> 5, cpi = idx & 31;
    int node = node0 + r;
    uint32_t u = (node < n) ? h2u[(size_t)node * 32 + cpi] : 0u;
    rows[r * 67 + 2 * cpi] = bf2f_lo(u);
    rows[r * 67 + 2 * cpi + 1] = bf2f_hi(u);
  }
  __syncthreads();
  if (t < 124) {
    int o = t / 62, i = t % 62;
    omean[t] = conv_b[o] + conv_w[o * 3] * cm[i] + conv_w[o * 3 + 1] * cm[i + 1] +
               conv_w[o * 3 + 2] * cm[i + 2];
  }
  __syncthreads();
  int node = node0 + t;
  if (node < n) {
    float r0[HID];
#pragma unroll
    for (int k = 0; k < HID; k++) r0[k] = rows[t * 67 + k];
    float w00 = conv_w[0], w01 = conv_w[1], w02 = conv_w[2];
    float w10 = conv_w[3], w11 = conv_w[4], w12 = conv_w[5];
    float b0 = conv_b[0], b1 = conv_b[1];
    float acc = 0.f;
#pragma unroll
    for (int i = 0; i < 62; i++) {
      float y0 = b0 + w00 * r0[i] + w01 * r0[i + 1] + w02 * r0[i + 2];
      float d0 = y0 - omean[i] + 1e-6f;
      acc += d0 * d0;
      float y1 = b1 + w10 * r0[i] + w11 * r0[i + 1] + w12 * r0[i + 2];
      float d1 = y1 - omean[62 + i] + 1e-6f;
      acc += d1 * d1;
    }
    float radius = sqrtf(acc);
    float dis = fminf(fmaxf(radius - ref_radius[0], 1e-4f), 1.f - 1e-4f);
    out[node] = dis;
  }
  if (blockIdx.x == 0 && t == 0) out[n] = ref_radius[0];
}

extern "C" void kernel_launch(void* const* d_in, const int* in_sizes, int n_in,
                              void* d_out, int out_size, void* d_ws, size_t ws_size,
                              hipStream_t stream) {
  const float* feat = (const float*)d_in[0];
  const float* w1 = (const float*)d_in[1];
  const float* w2 = (const float*)d_in[2];
  const float* conv_w = (const float*)d_in[3];
  const float* conv_b = (const float*)d_in[4];
  const float* ref_radius = (const float*)d_in[5];
  const int* src = (const int*)d_in[6];
  const int* dst = (const int*)d_in[7];
  int n = in_sizes[0] / INDIM;
  int E = in_sizes[6];
  float* out = (float*)d_out;

  int NB = (n + 255) >> 8;                 // 391 blocks of 256 nodes

  char* p = (char*)d_ws;
  auto carve = [&](size_t bytes) { void* r = (void*)p; p += (bytes + 255) & ~(size_t)255; return r; };
  float* norm = (float*)carve((size_t)n * 4);
  float* colsumR = (float*)carve((size_t)CSREP * HID * 4);
  int* rowstart = (int*)carve(((size_t)n + 1) * 4);
  int* deg = (int*)carve((size_t)n * 4);
  int* scn = (int*)carve((size_t)n * 4);
  int* btot = (int*)carve((size_t)NB * 4);
  int* cursor = (int*)carve((size_t)n * 4);
  int* csr = (int*)carve((size_t)E * 4);
  unsigned short* w1t = (unsigned short*)carve((size_t)INDIM * HID * 2);
  unsigned short* w2t = (unsigned short*)carve((size_t)HID * HID * 2);
  unsigned char* H0f8 = (unsigned char*)carve((size_t)n * HID);
  unsigned char* Tf8 = (unsigned char*)carve((size_t)n * HID);
  unsigned short* H2bf = (unsigned short*)carve((size_t)n * HID * 2);

  uint32_t k1a, k1b, k2a, k2b;
  tf2x32(0u, 42u, 0u, 0u, k1a, k1b);
  tf2x32(0u, 42u, 0u, 1u, k2a, k2b);

  int edgeB = (E + 255) / 256;             // 6250
  int gatherB = (n + 15) / 16;             // wave per 4 nodes, 4 waves per block
  int stripB = ((n + 15) / 16 + 3) / 4;    // wave per 16-node strip

  hipMemsetAsync(deg, 0, (size_t)n * 4, stream);
  hist_k<<<edgeB, 256, 0, stream>>>(dst, deg, w1, w2, w1t, w2t, colsumR, E);
  scan1_k<<<NB, 256, 0, stream>>>(deg, scn, btot, n);
  scan2_k<<<NB, 256, 0, stream>>>(scn, btot, deg, rowstart, cursor, norm, n, E);
  scat_k<<<edgeB, 256, 0, stream>>>(src, dst, cursor, csr, E);
  gemm1<<<stripB, 256, 0, stream>>>(feat, w1t, norm, H0f8, n);
  gather_k<<<gatherB, 256, 0, stream>>>((const uint32_t*)H0f8, (uint32_t*)Tf8, rowstart, csr, norm, n, k1a, k1b);
  gather2gemm2_k<<<gatherB, 256, 0, stream>>>((const uint32_t*)Tf8, rowstart, csr, norm, w2t, H2bf, colsumR, n, k2a, k2b);
  final_k<<<(n + 127) / 128, 128, 0, stream>>>((const uint32_t*)H2bf, colsumR, conv_w, conv_b, ref_radius, out, n);
}

// Round 9
// 236.888 us; speedup vs baseline: 1.7036x; 1.7036x over previous
//
#include <hip/hip_runtime.h>
#include <stdint.h>

#define HID 64
#define INDIM 128
#define NBK 512        // scan width >= NB (391) and >= NBLK (512)
#define NBLK 512       // binsort producer blocks
#define EPBCAP 3200    // max edges per binsort block (actual 3125)
#define BK3CAP 8192    // max edges per bucket (mean ~4092, sd ~64)
#define CSREP 32       // colsum atomic replicas (breaks same-line contention)

typedef __attribute__((ext_vector_type(8))) short bf16x8;
typedef __attribute__((ext_vector_type(4))) float f32x4;
typedef __attribute__((ext_vector_type(2))) float f32x2;

__host__ __device__ __forceinline__ void tf2x32(uint32_t k0, uint32_t k1,
                                                uint32_t x0, uint32_t x1,
                                                uint32_t& o0, uint32_t& o1) {
  uint32_t ks2 = k0 ^ k1 ^ 0x1BD11BDAu;
#define ROTL(v, r) (((v) << (r)) | ((v) >> (32 - (r))))
#define RND(r) { x0 += x1; x1 = ROTL(x1, r); x1 ^= x0; }
  x0 += k0; x1 += k1;
  RND(13) RND(15) RND(26) RND(6)
  x0 += k1; x1 += ks2 + 1u;
  RND(17) RND(29) RND(16) RND(24)
  x0 += ks2; x1 += k0 + 2u;
  RND(13) RND(15) RND(26) RND(6)
  x0 += k0; x1 += k1 + 3u;
  RND(17) RND(29) RND(16) RND(24)
  x0 += k1; x1 += ks2 + 4u;
  RND(13) RND(15) RND(26) RND(6)
  x0 += ks2; x1 += k0 + 5u;
  o0 = x0; o1 = x1;
#undef RND
#undef ROTL
}

__device__ __forceinline__ float tf_uniform(uint32_t ka, uint32_t kb, uint32_t j) {
  uint32_t o0, o1;
  tf2x32(ka, kb, 0u, j, o0, o1);
  uint32_t bits = o0 ^ o1;
  uint32_t f = (bits >> 9) | 0x3f800000u;
  return __uint_as_float(f) - 1.0f;
}

__device__ __forceinline__ unsigned short f2bf(float f) {
  uint32_t x = __float_as_uint(f);
  uint32_t r = (x + 0x7fffu + ((x >> 16) & 1u)) >> 16;   // RNE
  return (unsigned short)r;
}

__device__ __forceinline__ float bf2f_lo(uint32_t u) { return __uint_as_float(u << 16); }
__device__ __forceinline__ float bf2f_hi(uint32_t u) { return __uint_as_float(u & 0xffff0000u); }

__device__ __forceinline__ unsigned char f2fp8(float v) {
  return (unsigned char)(__builtin_amdgcn_cvt_pk_fp8_f32(v, 0.f, 0, false) & 0xff);
}

// K1: per-block counting sort of edges by bucket (dst>>8). No global atomics.
// LDS-staged -> all global writes coalesced (random 4B scatters amplify 16x
// at HBM: round-8 lesson, scat_k wrote 105MB for a 6.4MB payload).
// Prologue absorbs wcvt (w1t/w2t transpose-convert, colsumR zero).
__global__ __launch_bounds__(256) void binsort_k(const int* __restrict__ src,
                                                 const int* __restrict__ dst,
                                                 uint32_t* __restrict__ sorted,
                                                 int* __restrict__ blockoff2,
                                                 const float* __restrict__ w1,
                                                 const float* __restrict__ w2,
                                                 unsigned short* __restrict__ w1t,
                                                 unsigned short* __restrict__ w2t,
                                                 float* __restrict__ colsumR,
                                                 int E, int EPB, int NB) {
  __shared__ uint32_t lbuf[EPBCAP];
  __shared__ int dbuf[EPBCAP];
  __shared__ int ha[NBK], hb[NBK], cursor[NBK];
  int b = blockIdx.x, t = threadIdx.x;
  {
    int i = b * 256 + t;
    if (i < CSREP * HID) colsumR[i] = 0.f;
    if (i < INDIM * HID) {
      int c = i >> 7, k = i & 127;
      w1t[i] = f2bf(w1[k * HID + c]);
    } else if (i < INDIM * HID + HID * HID) {
      int j = i - INDIM * HID;
      int c = j >> 6, k = j & 63;
      w2t[j] = f2bf(w2[k * HID + c]);
    }
  }
  int e0 = b * EPB;
  int e1 = e0 + EPB; if (e1 > E) e1 = E;
  int m = e1 - e0;
  ha[t] = 0; ha[t + 256] = 0;
  __syncthreads();
  for (int i = t; i < m; i += 256) {
    int d = dst[e0 + i];
    dbuf[i] = d;
    atomicAdd(&ha[d >> 8], 1);
  }
  __syncthreads();
  int* cur = ha; int* nxt = hb;
  for (int off = 1; off < 512; off <<= 1) {
    int i0 = t, i1 = t + 256;
    int v0 = cur[i0] + ((i0 >= off) ? cur[i0 - off] : 0);
    int v1 = cur[i1] + ((i1 >= off) ? cur[i1 - off] : 0);
    __syncthreads();
    nxt[i0] = v0; nxt[i1] = v1;
    __syncthreads();
    int* tmp = cur; cur = nxt; nxt = tmp;
  }
  for (int i = t; i < NB; i += 256) {
    int ex = (i == 0) ? 0 : cur[i - 1];
    cursor[i] = ex;
    blockoff2[(size_t)i * NBLK + b] = ex;
  }
  if (t == 0) blockoff2[(size_t)NB * NBLK + b] = m;
  __syncthreads();
  for (int i = t; i < m; i += 256) {
    int d = dbuf[i], s = src[e0 + i];
    int pos = atomicAdd(&cursor[d >> 8], 1);
    lbuf[pos] = ((uint32_t)s << 8) | (uint32_t)(d & 255);
  }
  __syncthreads();
  for (int i = t; i < m; i += 256) sorted[e0 + i] = lbuf[i];
}

// K3 (fused boff+bscan+csrbuild): one block per bucket.
// Segment gather now uses 8-lane cooperative groups over LDS-staged
// descriptors -> ~8-edge segments load as one coalesced 32B transaction.
__global__ __launch_bounds__(256) void csrbuild_k(const uint32_t* __restrict__ sorted,
                                                  const int* __restrict__ blockoff2,
                                                  int* __restrict__ rowstart,
                                                  int* __restrict__ csr,
                                                  float* __restrict__ norm,
                                                  int NB, int n, int E, int EPB) {
  __shared__ uint32_t ebuf[BK3CAP];
  __shared__ int sa[256], sb[256], cursor[256];
  __shared__ int sc_[NBLK], sd_[NBLK];
  __shared__ int seglo[NBLK], segdd[NBLK], seglen[NBLK];
  int bid = blockIdx.x, t = threadIdx.x;
  int xcd = bid & 7, sub = bid >> 3;
  int qq = NB >> 3, rr = NB & 7;
  int k = (xcd < rr ? xcd * (qq + 1) : rr * (qq + 1) + (xcd - rr) * qq) + sub;

  int b0 = t, b1 = t + 256;
  int lo0 = blockoff2[(size_t)k * NBLK + b0];
  int lo1 = blockoff2[(size_t)k * NBLK + b1];
  int hi0 = blockoff2[(size_t)(k + 1) * NBLK + b0];
  int hi1 = blockoff2[(size_t)(k + 1) * NBLK + b1];
  int len0 = hi0 - lo0, len1 = hi1 - lo1;
  sa[t] = lo0 + lo1;
  sc_[b0] = len0; sc_[b1] = len1;
  seglo[b0] = lo0; seglo[b1] = lo1;
  seglen[b0] = len0; seglen[b1] = len1;
  __syncthreads();
  for (int off = 128; off > 0; off >>= 1) {
    if (t < off) sa[t] += sa[t + off];
    __syncthreads();
  }
  int s0 = sa[0];
  int* cur = sc_; int* nxt = sd_;
  for (int off = 1; off < NBLK; off <<= 1) {
    int v0 = cur[b0] + ((b0 >= off) ? cur[b0 - off] : 0);
    int v1 = cur[b1] + ((b1 >= off) ? cur[b1 - off] : 0);
    __syncthreads();
    nxt[b0] = v0; nxt[b1] = v1;
    __syncthreads();
    int* tmp = cur; cur = nxt; nxt = tmp;
  }
  int M = cur[NBLK - 1];
  segdd[b0] = cur[b0] - len0;
  segdd[b1] = cur[b1] - len1;
  __syncthreads();
  // cooperative segment copy: 32 groups of 8 lanes; group gr walks segments
  // gr, gr+32, ... ; lanes load consecutive edges (coalesced 32B typical).
  {
    int gr = t >> 3, l8 = t & 7;
    for (int s = gr; s < NBLK; s += 32) {
      int lo = seglo[s], dd = segdd[s], ln = seglen[s];
      const uint32_t* sp = sorted + (size_t)s * EPB;
      for (int j = l8; j < ln; j += 8) ebuf[dd + j] = sp[lo + j];
    }
  }
  cursor[t] = 0;
  __syncthreads();
  for (int i = t; i < M; i += 256) atomicAdd(&cursor[ebuf[i] & 255], 1);
  __syncthreads();
  int cnt = cursor[t];
  sa[t] = cnt;
  int* cu2 = sa; int* nx2 = sb;
  __syncthreads();
  for (int off = 1; off < 256; off <<= 1) {
    int v = cu2[t] + ((t >= off) ? cu2[t - off] : 0);
    __syncthreads();
    nx2[t] = v;
    __syncthreads();
    int* tmp = cu2; cu2 = nx2; nx2 = tmp;
  }
  int localrow = cu2[t] - cnt;
  int node = k * 256 + t;
  if (node < n) {
    rowstart[node] = s0 + localrow;
    norm[node] = rsqrtf((float)(cnt + 1));
  }
  if (k == NB - 1 && t == 255) rowstart[n] = E;
  cursor[t] = localrow;
  __syncthreads();
  for (int i = t; i < M; i += 256) {
    uint32_t pe = ebuf[i];
    int pos = atomicAdd(&cursor[pe & 255], 1);
    csr[s0 + pos] = (int)(pe >> 8);
  }
}

// MFMA gemm1: h0 = fp8(norm * (feat @ w1)). One wave per 16-node strip.
__global__ __launch_bounds__(256) void gemm1(const float* __restrict__ feat,
                                             const unsigned short* __restrict__ w1t,
                                             const float* __restrict__ norm,
                                             unsigned char* __restrict__ h0, int n) {
  int t = threadIdx.x;
  int wv = t >> 6, lane = t & 63;
  int strip = blockIdx.x * 4 + wv;
  if (strip * 16 >= n) return;
  int m = lane & 15, q = lane >> 4;
  bf16x8 Bf[4][4];
#pragma unroll
  for (int kc = 0; kc < 4; kc++)
#pragma unroll
    for (int ct = 0; ct < 4; ct++)
      Bf[kc][ct] = *(const bf16x8*)(w1t + (ct * 16 + m) * INDIM + kc * 32 + q * 8);
  const float* arow = feat + (size_t)(strip * 16 + m) * INDIM;
  bf16x8 Af[4];
#pragma unroll
  for (int kc = 0; kc < 4; kc++) {
    const float* pa = arow + kc * 32 + q * 8;
    bf16x8 a;
#pragma unroll
    for (int j = 0; j < 8; j++) a[j] = (short)f2bf(pa[j]);
    Af[kc] = a;
  }
  f32x4 acc[4] = {{0.f,0.f,0.f,0.f},{0.f,0.f,0.f,0.f},{0.f,0.f,0.f,0.f},{0.f,0.f,0.f,0.f}};
#pragma unroll
  for (int kc = 0; kc < 4; kc++)
#pragma unroll
    for (int ct = 0; ct < 4; ct++)
      acc[ct] = __builtin_amdgcn_mfma_f32_16x16x32_bf16(Af[kc], Bf[kc][ct], acc[ct], 0, 0, 0);
#pragma unroll
  for (int r = 0; r < 4; r++) {
    int row = strip * 16 + q * 4 + r;
    float nm = norm[row];
#pragma unroll
    for (int ct = 0; ct < 4; ct++)
      h0[(size_t)row * HID + ct * 16 + m] = f2fp8(acc[ct][r] * nm);
  }
}

// 4-node-per-wave CSR gather over fp8 rows, MODE 0 only:
// fused relu/dropout(ballot)/prescale -> fp8 out.
__global__ __launch_bounds__(256) void gather_k(const uint32_t* __restrict__ h8,
                                                uint32_t* __restrict__ outp,
                                                const int* __restrict__ rowstart,
                                                const int* __restrict__ csr,
                                                const float* __restrict__ norm,
                                                int n, uint32_t ka, uint32_t kb) {
  int wid = (int)((blockIdx.x * 256u + threadIdx.x) >> 6);
  int d0 = wid * 4;
  if (d0 >= n) return;
  int lane = threadIdx.x & 63;
  int g = lane >> 4, c4 = lane & 15;
  int g4 = g << 2;

  int rr = d0 + (lane < 4 ? lane : 4);
  if (rr > n) rr = n;
  int rsl = rowstart[rr];
  int r0[5];
#pragma unroll
  for (int i = 0; i < 5; ++i) r0[i] = __shfl(rsl, i);
  int L[4];
#pragma unroll
  for (int i = 0; i < 4; ++i) L[i] = r0[i + 1] - r0[i];

  int selfrow = d0 + g; if (selfrow >= n) selfrow = d0;
  uint32_t uself = h8[(size_t)selfrow * 16 + c4];

  int idx[4];
#pragma unroll
  for (int i = 0; i < 4; ++i) {
    int la = L[i] < 32 ? L[i] : 32;
    idx[i] = (lane < la) ? csr[r0[i] + lane] : 0;
  }

  uint32_t u[4][8];
#pragma unroll
  for (int i = 0; i < 4; ++i) {
#pragma unroll
    for (int t = 0; t < 8; ++t) {
      int s = __builtin_amdgcn_ds_bpermute(16 * t + g4, idx[i]);
      u[i][t] = (4 * t + g < L[i]) ? h8[(size_t)(uint32_t)s * 16 + c4] : 0u;
    }
  }

  f32x2 al[4], ah[4];
#pragma unroll
  for (int i = 0; i < 4; ++i) { al[i] = (f32x2){0.f, 0.f}; ah[i] = (f32x2){0.f, 0.f}; }
#pragma unroll
  for (int i = 0; i < 4; ++i) {
#pragma unroll
    for (int t = 0; t < 8; ++t) {
      al[i] += __builtin_amdgcn_cvt_pk_f32_fp8((int)u[i][t], false);
      ah[i] += __builtin_amdgcn_cvt_pk_f32_fp8((int)u[i][t], true);
    }
  }

#pragma unroll
  for (int i = 0; i < 4; ++i) {
    if (L[i] > 32) {
      for (int e0 = 32; e0 < L[i]; e0 += 4) {
        int e = e0 + g;
        uint32_t uu = 0u;
        if (e < L[i]) {
          int s = csr[r0[i] + e];
          uu = h8[(size_t)(uint32_t)s * 16 + c4];
        }
        al[i] += __builtin_amdgcn_cvt_pk_f32_fp8((int)uu, false);
        ah[i] += __builtin_amdgcn_cvt_pk_f32_fp8((int)uu, true);
      }
    }
  }

  f32x2 sl, sh, rl2, rh2;
  sl = (g & 1) ? al[0] : al[1];
  sh = (g & 1) ? ah[0] : ah[1];
  rl2.x = __shfl_xor(sl.x, 16); rl2.y = __shfl_xor(sl.y, 16);
  rh2.x = __shfl_xor(sh.x, 16); rh2.y = __shfl_xor(sh.y, 16);
  f32x2 fABl = ((g & 1) ? al[1] : al[0]) + rl2;
  f32x2 fABh = ((g & 1) ? ah[1] : ah[0]) + rh2;
  sl = (g & 1) ? al[2] : al[3];
  sh = (g & 1) ? ah[2] : ah[3];
  rl2.x = __shfl_xor(sl.x, 16); rl2.y = __shfl_xor(sl.y, 16);
  rh2.x = __shfl_xor(sh.x, 16); rh2.y = __shfl_xor(sh.y, 16);
  f32x2 fCDl = ((g & 1) ? al[3] : al[2]) + rl2;
  f32x2 fCDh = ((g & 1) ? ah[3] : ah[2]) + rh2;
  sl = (g & 2) ? fABl : fCDl;
  sh = (g & 2) ? fABh : fCDh;
  rl2.x = __shfl_xor(sl.x, 32); rl2.y = __shfl_xor(sl.y, 32);
  rh2.x = __shfl_xor(sh.x, 32); rh2.y = __shfl_xor(sh.y, 32);
  f32x2 tl = ((g & 2) ? fCDl : fABl) + rl2;
  f32x2 th = ((g & 2) ? fCDh : fABh) + rh2;

  tl += __builtin_amdgcn_cvt_pk_f32_fp8((int)uself, false);
  th += __builtin_amdgcn_cvt_pk_f32_fp8((int)uself, true);

  int d = d0 + g;
  uint32_t jb = (uint32_t)d0 * 64u + (uint32_t)lane;
  float u0 = tf_uniform(ka, kb, jb);
  float u1 = tf_uniform(ka, kb, jb + 64u);
  float u2 = tf_uniform(ka, kb, jb + 128u);
  float u3 = tf_uniform(ka, kb, jb + 192u);
  unsigned long long kp0 = __ballot(u0 < 0.5f);
  unsigned long long kp1 = __ballot(u1 < 0.5f);
  unsigned long long kp2 = __ballot(u2 < 0.5f);
  unsigned long long kp3 = __ballot(u3 < 0.5f);
  unsigned long long keep = (g & 2) ? ((g & 1) ? kp3 : kp2)
                                    : ((g & 1) ? kp1 : kp0);
  uint32_t kb4 = (uint32_t)(keep >> (4 * c4)) & 15u;
  float nm = norm[d < n ? d : d0];
  float v0 = fmaxf(tl.x * nm, 0.f), v1 = fmaxf(tl.y * nm, 0.f);
  float v2 = fmaxf(th.x * nm, 0.f), v3 = fmaxf(th.y * nm, 0.f);
  float s2 = 2.f * nm;
  v0 = (kb4 & 1u) ? v0 * s2 : 0.f;
  v1 = (kb4 & 2u) ? v1 * s2 : 0.f;
  v2 = (kb4 & 4u) ? v2 * s2 : 0.f;
  v3 = (kb4 & 8u) ? v3 * s2 : 0.f;
  if (d < n) {
    int o = __builtin_amdgcn_cvt_pk_fp8_f32(v0, v1, 0, false);
    o = __builtin_amdgcn_cvt_pk_fp8_f32(v2, v3, o, true);
    outp[(size_t)d * 16 + c4] = (uint32_t)o;
  }
}

// Fused gather<1> + gemm2: block = one 16-node strip (4 waves x 4 nodes).
__global__ __launch_bounds__(256) void gather2gemm2_k(
    const uint32_t* __restrict__ h8, const int* __restrict__ rowstart,
    const int* __restrict__ csr, const float* __restrict__ norm,
    const unsigned short* __restrict__ w2t, unsigned short* __restrict__ h2,
    float* __restrict__ colsumR, int n, uint32_t ka, uint32_t kb) {
  __shared__ unsigned short abuf[16][72];   // +8 pad breaks bank conflicts
  int t = threadIdx.x;
  int wv = t >> 6, lane = t & 63;
  int node0 = blockIdx.x * 16;
  int d0 = node0 + wv * 4;
  int g = lane >> 4, c4 = lane & 15;
  int g4 = g << 2;
  int lrow = (wv << 2) + g;

  if (d0 < n) {
    int rr = d0 + (lane < 4 ? lane : 4);
    if (rr > n) rr = n;
    int rsl = rowstart[rr];
    int r0[5];
#pragma unroll
    for (int i = 0; i < 5; ++i) r0[i] = __shfl(rsl, i);
    int L[4];
#pragma unroll
    for (int i = 0; i < 4; ++i) L[i] = r0[i + 1] - r0[i];

    int selfrow = d0 + g; if (selfrow >= n) selfrow = d0;
    uint32_t uself = h8[(size_t)selfrow * 16 + c4];

    int idx[4];
#pragma unroll
    for (int i = 0; i < 4; ++i) {
      int la = L[i] < 32 ? L[i] : 32;
      idx[i] = (lane < la) ? csr[r0[i] + lane] : 0;
    }

    uint32_t u[4][8];
#pragma unroll
    for (int i = 0; i < 4; ++i) {
#pragma unroll
      for (int tt = 0; tt < 8; ++tt) {
        int s = __builtin_amdgcn_ds_bpermute(16 * tt + g4, idx[i]);
        u[i][tt] = (4 * tt + g < L[i]) ? h8[(size_t)(uint32_t)s * 16 + c4] : 0u;
      }
    }

    f32x2 al[4], ah[4];
#pragma unroll
    for (int i = 0; i < 4; ++i) { al[i] = (f32x2){0.f, 0.f}; ah[i] = (f32x2){0.f, 0.f}; }
#pragma unroll
    for (int i = 0; i < 4; ++i) {
#pragma unroll
      for (int tt = 0; tt < 8; ++tt) {
        al[i] += __builtin_amdgcn_cvt_pk_f32_fp8((int)u[i][tt], false);
        ah[i] += __builtin_amdgcn_cvt_pk_f32_fp8((int)u[i][tt], true);
      }
    }

#pragma unroll
    for (int i = 0; i < 4; ++i) {
      if (L[i] > 32) {
        for (int e0 = 32; e0 < L[i]; e0 += 4) {
          int e = e0 + g;
          uint32_t uu = 0u;
          if (e < L[i]) {
            int s = csr[r0[i] + e];
            uu = h8[(size_t)(uint32_t)s * 16 + c4];
          }
          al[i] += __builtin_amdgcn_cvt_pk_f32_fp8((int)uu, false);
          ah[i] += __builtin_amdgcn_cvt_pk_f32_fp8((int)uu, true);
        }
      }
    }

    f32x2 sl, sh, rl2, rh2;
    sl = (g & 1) ? al[0] : al[1];
    sh = (g & 1) ? ah[0] : ah[1];
    rl2.x = __shfl_xor(sl.x, 16); rl2.y = __shfl_xor(sl.y, 16);
    rh2.x = __shfl_xor(sh.x, 16); rh2.y = __shfl_xor(sh.y, 16);
    f32x2 fABl = ((g & 1) ? al[1] : al[0]) + rl2;
    f32x2 fABh = ((g & 1) ? ah[1] : ah[0]) + rh2;
    sl = (g & 1) ? al[2] : al[3];
    sh = (g & 1) ? ah[2] : ah[3];
    rl2.x = __shfl_xor(sl.x, 16); rl2.y = __shfl_xor(sl.y, 16);
    rh2.x = __shfl_xor(sh.x, 16); rh2.y = __shfl_xor(sh.y, 16);
    f32x2 fCDl = ((g & 1) ? al[3] : al[2]) + rl2;
    f32x2 fCDh = ((g & 1) ? ah[3] : ah[2]) + rh2;
    sl = (g & 2) ? fABl : fCDl;
    sh = (g & 2) ? fABh : fCDh;
    rl2.x = __shfl_xor(sl.x, 32); rl2.y = __shfl_xor(sl.y, 32);
    rh2.x = __shfl_xor(sh.x, 32); rh2.y = __shfl_xor(sh.y, 32);
    f32x2 tl = ((g & 2) ? fCDl : fABl) + rl2;
    f32x2 th = ((g & 2) ? fCDh : fABh) + rh2;

    tl += __builtin_amdgcn_cvt_pk_f32_fp8((int)uself, false);
    th += __builtin_amdgcn_cvt_pk_f32_fp8((int)uself, true);

    uint2 w;
    w.x = (uint32_t)f2bf(tl.x) | ((uint32_t)f2bf(tl.y) << 16);
    w.y = (uint32_t)f2bf(th.x) | ((uint32_t)f2bf(th.y) << 16);
    if (d0 + g >= n) { w.x = 0u; w.y = 0u; }
    *(uint2*)&abuf[lrow][4 * c4] = w;
  } else {
    uint2 z; z.x = 0u; z.y = 0u;
    *(uint2*)&abuf[lrow][4 * c4] = z;
  }
  __syncthreads();
  if (wv != 0) return;
  if (node0 >= n) return;

  int m = lane & 15, q = lane >> 4;
  f32x4 acc[4] = {{0.f,0.f,0.f,0.f},{0.f,0.f,0.f,0.f},{0.f,0.f,0.f,0.f},{0.f,0.f,0.f,0.f}};
#pragma unroll
  for (int kc = 0; kc < 2; kc++) {
    bf16x8 Af = *(const bf16x8*)&abuf[m][kc * 32 + q * 8];
#pragma unroll
    for (int ct = 0; ct < 4; ct++) {
      bf16x8 Bf = *(const bf16x8*)(w2t + (ct * 16 + m) * HID + kc * 32 + q * 8);
      acc[ct] = __builtin_amdgcn_mfma_f32_16x16x32_bf16(Af, Bf, acc[ct], 0, 0, 0);
    }
  }
  float cs[4] = {0.f, 0.f, 0.f, 0.f};
#pragma unroll
  for (int r = 0; r < 4; r++) {
    int row = node0 + q * 4 + r;
    if (row < n) {
      float nm = norm[row];
#pragma unroll
      for (int ct = 0; ct < 4; ct++) {
        int col = ct * 16 + m;
        float v = fmaxf(acc[ct][r] * nm, 0.f);
        float uu = tf_uniform(ka, kb, (uint32_t)row * 64u + (uint32_t)col);
        v = (uu < 0.5f) ? v * 2.f : 0.f;
        h2[(size_t)row * HID + col] = f2bf(v);
        cs[ct] += v;
      }
    }
  }
#pragma unroll
  for (int ct = 0; ct < 4; ct++) {
    cs[ct] += __shfl_xor(cs[ct], 16);
    cs[ct] += __shfl_xor(cs[ct], 32);
  }
  if (q == 0) {
    float* dstc = colsumR + (blockIdx.x & (CSREP - 1)) * HID;
#pragma unroll
    for (int ct = 0; ct < 4; ct++) atomicAdd(&dstc[ct * 16 + m], cs[ct]);
  }
}

__global__ __launch_bounds__(128) void final_k(const uint32_t* __restrict__ h2u,
                                               const float* __restrict__ colsumR,
                                               const float* __restrict__ conv_w,
                                               const float* __restrict__ conv_b,
                                               const float* __restrict__ ref_radius,
                                               float* __restrict__ out, int n) {
  __shared__ float rows[128 * 67];
  __shared__ float omean[124];
  __shared__ float cm[HID];
  int t = threadIdx.x;
  int node0 = blockIdx.x * 128;
  if (t < HID) {
    float s = 0.f;
#pragma unroll
    for (int r = 0; r < CSREP; r++) s += colsumR[r * HID + t];
    cm[t] = s * (1.0f / (float)n);
  }
  for (int idx = t; idx < 128 * 32; idx += 128) {
    int r = idx >> 5, cpi = idx & 31;
    int node = node0 + r;
    uint32_t u = (node < n) ? h2u[(size_t)node * 32 + cpi] : 0u;
    rows[r * 67 + 2 * cpi] = bf2f_lo(u);
    rows[r * 67 + 2 * cpi + 1] = bf2f_hi(u);
  }
  __syncthreads();
  if (t < 124) {
    int o = t / 62, i = t % 62;
    omean[t] = conv_b[o] + conv_w[o * 3] * cm[i] + conv_w[o * 3 + 1] * cm[i + 1] +
               conv_w[o * 3 + 2] * cm[i + 2];
  }
  __syncthreads();
  int node = node0 + t;
  if (node < n) {
    float r0[HID];
#pragma unroll
    for (int k = 0; k < HID; k++) r0[k] = rows[t * 67 + k];
    float w00 = conv_w[0], w01 = conv_w[1], w02 = conv_w[2];
    float w10 = conv_w[3], w11 = conv_w[4], w12 = conv_w[5];
    float b0 = conv_b[0], b1 = conv_b[1];
    float acc = 0.f;
#pragma unroll
    for (int i = 0; i < 62; i++) {
      float y0 = b0 + w00 * r0[i] + w01 * r0[i + 1] + w02 * r0[i + 2];
      float d0 = y0 - omean[i] + 1e-6f;
      acc += d0 * d0;
      float y1 = b1 + w10 * r0[i] + w11 * r0[i + 1] + w12 * r0[i + 2];
      float d1 = y1 - omean[62 + i] + 1e-6f;
      acc += d1 * d1;
    }
    float radius = sqrtf(acc);
    float dis = fminf(fmaxf(radius - ref_radius[0], 1e-4f), 1.f - 1e-4f);
    out[node] = dis;
  }
  if (blockIdx.x == 0 && t == 0) out[n] = ref_radius[0];
}

extern "C" void kernel_launch(void* const* d_in, const int* in_sizes, int n_in,
                              void* d_out, int out_size, void* d_ws, size_t ws_size,
                              hipStream_t stream) {
  const float* feat = (const float*)d_in[0];
  const float* w1 = (const float*)d_in[1];
  const float* w2 = (const float*)d_in[2];
  const float* conv_w = (const float*)d_in[3];
  const float* conv_b = (const float*)d_in[4];
  const float* ref_radius = (const float*)d_in[5];
  const int* src = (const int*)d_in[6];
  const int* dst = (const int*)d_in[7];
  int n = in_sizes[0] / INDIM;
  int E = in_sizes[6];
  float* out = (float*)d_out;

  int NB = (n + 255) >> 8;                 // 391 buckets of 256 nodes
  int EPB = (E + NBLK - 1) / NBLK;         // 3125 edges per binsort block

  char* p = (char*)d_ws;
  auto carve = [&](size_t bytes) { void* r = (void*)p; p += (bytes + 255) & ~(size_t)255; return r; };
  float* norm = (float*)carve((size_t)n * 4);
  float* colsumR = (float*)carve((size_t)CSREP * HID * 4);
  int* rowstart = (int*)carve(((size_t)n + 1) * 4);
  int* blockoff2 = (int*)carve((size_t)(NB + 1) * NBLK * 4);   // [bucket][block]
  uint32_t* sorted = (uint32_t*)carve((size_t)E * 4);
  int* csr = (int*)carve((size_t)E * 4);
  unsigned short* w1t = (unsigned short*)carve((size_t)INDIM * HID * 2);
  unsigned short* w2t = (unsigned short*)carve((size_t)HID * HID * 2);
  unsigned char* H0f8 = (unsigned char*)carve((size_t)n * HID);
  unsigned char* Tf8 = (unsigned char*)carve((size_t)n * HID);
  unsigned short* H2bf = (unsigned short*)carve((size_t)n * HID * 2);

  uint32_t k1a, k1b, k2a, k2b;
  tf2x32(0u, 42u, 0u, 0u, k1a, k1b);
  tf2x32(0u, 42u, 0u, 1u, k2a, k2b);

  int gatherB = (n + 15) / 16;             // wave per 4 nodes, 4 waves per block
  int stripB = ((n + 15) / 16 + 3) / 4;    // wave per 16-node strip

  binsort_k<<<NBLK, 256, 0, stream>>>(src, dst, sorted, blockoff2, w1, w2, w1t, w2t, colsumR, E, EPB, NB);
  csrbuild_k<<<NB, 256, 0, stream>>>(sorted, blockoff2, rowstart, csr, norm, NB, n, E, EPB);
  gemm1<<<stripB, 256, 0, stream>>>(feat, w1t, norm, H0f8, n);
  gather_k<<<gatherB, 256, 0, stream>>>((const uint32_t*)H0f8, (uint32_t*)Tf8, rowstart, csr, norm, n, k1a, k1b);
  gather2gemm2_k<<<gatherB, 256, 0, stream>>>((const uint32_t*)Tf8, rowstart, csr, norm, w2t, H2bf, colsumR, n, k2a, k2b);
  final_k<<<(n + 127) / 128, 128, 0, stream>>>((const uint32_t*)H2bf, colsumR, conv_w, conv_b, ref_radius, out, n);
}

// Round 10
// 228.032 us; speedup vs baseline: 1.7697x; 1.0388x over previous
//
#include <hip/hip_runtime.h>
#include <stdint.h>

#define HID 64
#define INDIM 128
#define NBK 512        // scan width >= NB (391) and >= NBLK (512)
#define NBLK 512       // binsort producer blocks
#define EPBCAP 3200    // max edges per binsort block (actual 3125)
#define BK3CAP 8192    // max edges per bucket (mean ~4092, sd ~64)
#define CSREP 32       // colsum atomic replicas (breaks same-line contention)

typedef __attribute__((ext_vector_type(8))) short bf16x8;
typedef __attribute__((ext_vector_type(4))) float f32x4;
typedef __attribute__((ext_vector_type(2))) float f32x2;

__host__ __device__ __forceinline__ void tf2x32(uint32_t k0, uint32_t k1,
                                                uint32_t x0, uint32_t x1,
                                                uint32_t& o0, uint32_t& o1) {
  uint32_t ks2 = k0 ^ k1 ^ 0x1BD11BDAu;
#define ROTL(v, r) (((v) << (r)) | ((v) >> (32 - (r))))
#define RND(r) { x0 += x1; x1 = ROTL(x1, r); x1 ^= x0; }
  x0 += k0; x1 += k1;
  RND(13) RND(15) RND(26) RND(6)
  x0 += k1; x1 += ks2 + 1u;
  RND(17) RND(29) RND(16) RND(24)
  x0 += ks2; x1 += k0 + 2u;
  RND(13) RND(15) RND(26) RND(6)
  x0 += k0; x1 += k1 + 3u;
  RND(17) RND(29) RND(16) RND(24)
  x0 += k1; x1 += ks2 + 4u;
  RND(13) RND(15) RND(26) RND(6)
  x0 += ks2; x1 += k0 + 5u;
  o0 = x0; o1 = x1;
#undef RND
#undef ROTL
}

__device__ __forceinline__ float tf_uniform(uint32_t ka, uint32_t kb, uint32_t j) {
  uint32_t o0, o1;
  tf2x32(ka, kb, 0u, j, o0, o1);
  uint32_t bits = o0 ^ o1;
  uint32_t f = (bits >> 9) | 0x3f800000u;
  return __uint_as_float(f) - 1.0f;
}

__device__ __forceinline__ unsigned short f2bf(float f) {
  uint32_t x = __float_as_uint(f);
  uint32_t r = (x + 0x7fffu + ((x >> 16) & 1u)) >> 16;   // RNE
  return (unsigned short)r;
}

__device__ __forceinline__ float bf2f_lo(uint32_t u) { return __uint_as_float(u << 16); }
__device__ __forceinline__ float bf2f_hi(uint32_t u) { return __uint_as_float(u & 0xffff0000u); }

__device__ __forceinline__ unsigned char f2fp8(float v) {
  return (unsigned char)(__builtin_amdgcn_cvt_pk_fp8_f32(v, 0.f, 0, false) & 0xff);
}

// K1: per-block counting sort of edges by bucket (dst>>8). No global atomics.
// LDS-staged -> all global writes coalesced (random 4B scatters amplify 16x
// at HBM: round-8 lesson, scat_k wrote 105MB for a 6.4MB payload).
// Prologue absorbs wcvt (w1t/w2t transpose-convert, colsumR zero).
__global__ __launch_bounds__(256) void binsort_k(const int* __restrict__ src,
                                                 const int* __restrict__ dst,
                                                 uint32_t* __restrict__ sorted,
                                                 int* __restrict__ blockoff2,
                                                 const float* __restrict__ w1,
                                                 const float* __restrict__ w2,
                                                 unsigned short* __restrict__ w1t,
                                                 unsigned short* __restrict__ w2t,
                                                 float* __restrict__ colsumR,
                                                 int E, int EPB, int NB) {
  __shared__ uint32_t lbuf[EPBCAP];
  __shared__ int dbuf[EPBCAP];
  __shared__ int ha[NBK], hb[NBK], cursor[NBK];
  int b = blockIdx.x, t = threadIdx.x;
  {
    int i = b * 256 + t;
    if (i < CSREP * HID) colsumR[i] = 0.f;
    if (i < INDIM * HID) {
      int c = i >> 7, k = i & 127;
      w1t[i] = f2bf(w1[k * HID + c]);
    } else if (i < INDIM * HID + HID * HID) {
      int j = i - INDIM * HID;
      int c = j >> 6, k = j & 63;
      w2t[j] = f2bf(w2[k * HID + c]);
    }
  }
  int e0 = b * EPB;
  int e1 = e0 + EPB; if (e1 > E) e1 = E;
  int m = e1 - e0;
  ha[t] = 0; ha[t + 256] = 0;
  __syncthreads();
  for (int i = t; i < m; i += 256) {
    int d = dst[e0 + i];
    dbuf[i] = d;
    atomicAdd(&ha[d >> 8], 1);
  }
  __syncthreads();
  int* cur = ha; int* nxt = hb;
  for (int off = 1; off < 512; off <<= 1) {
    int i0 = t, i1 = t + 256;
    int v0 = cur[i0] + ((i0 >= off) ? cur[i0 - off] : 0);
    int v1 = cur[i1] + ((i1 >= off) ? cur[i1 - off] : 0);
    __syncthreads();
    nxt[i0] = v0; nxt[i1] = v1;
    __syncthreads();
    int* tmp = cur; cur = nxt; nxt = tmp;
  }
  for (int i = t; i < NB; i += 256) {
    int ex = (i == 0) ? 0 : cur[i - 1];
    cursor[i] = ex;
    blockoff2[(size_t)i * NBLK + b] = ex;
  }
  if (t == 0) blockoff2[(size_t)NB * NBLK + b] = m;
  __syncthreads();
  for (int i = t; i < m; i += 256) {
    int d = dbuf[i], s = src[e0 + i];
    int pos = atomicAdd(&cursor[d >> 8], 1);
    lbuf[pos] = ((uint32_t)s << 8) | (uint32_t)(d & 255);
  }
  __syncthreads();
  for (int i = t; i < m; i += 256) sorted[e0 + i] = lbuf[i];
}

// K3 (fused boff+bscan+csrbuild): one block per bucket.
// Per-thread segment copy (round-7 proven; coop-copy variant measured worse).
__global__ __launch_bounds__(256) void csrbuild_k(const uint32_t* __restrict__ sorted,
                                                  const int* __restrict__ blockoff2,
                                                  int* __restrict__ rowstart,
                                                  int* __restrict__ csr,
                                                  float* __restrict__ norm,
                                                  int NB, int n, int E, int EPB) {
  __shared__ uint32_t ebuf[BK3CAP];
  __shared__ int sa[256], sb[256], cursor[256];
  __shared__ int sc_[NBLK], sd_[NBLK];
  int bid = blockIdx.x, t = threadIdx.x;
  int xcd = bid & 7, sub = bid >> 3;
  int qq = NB >> 3, rr = NB & 7;
  int k = (xcd < rr ? xcd * (qq + 1) : rr * (qq + 1) + (xcd - rr) * qq) + sub;

  int b0 = t, b1 = t + 256;
  int lo0 = blockoff2[(size_t)k * NBLK + b0];
  int lo1 = blockoff2[(size_t)k * NBLK + b1];
  int hi0 = blockoff2[(size_t)(k + 1) * NBLK + b0];
  int hi1 = blockoff2[(size_t)(k + 1) * NBLK + b1];
  int len0 = hi0 - lo0, len1 = hi1 - lo1;
  sa[t] = lo0 + lo1;
  sc_[b0] = len0; sc_[b1] = len1;
  __syncthreads();
  for (int off = 128; off > 0; off >>= 1) {
    if (t < off) sa[t] += sa[t + off];
    __syncthreads();
  }
  int s0 = sa[0];
  int* cur = sc_; int* nxt = sd_;
  for (int off = 1; off < NBLK; off <<= 1) {
    int v0 = cur[b0] + ((b0 >= off) ? cur[b0 - off] : 0);
    int v1 = cur[b1] + ((b1 >= off) ? cur[b1 - off] : 0);
    __syncthreads();
    nxt[b0] = v0; nxt[b1] = v1;
    __syncthreads();
    int* tmp = cur; cur = nxt; nxt = tmp;
  }
  int M = cur[NBLK - 1];
  int dd0 = cur[b0] - len0, dd1 = cur[b1] - len1;
  {
    const uint32_t* sp = sorted + (size_t)b0 * EPB;
    for (int i = lo0; i < hi0; i++) ebuf[dd0 + (i - lo0)] = sp[i];
  }
  {
    const uint32_t* sp = sorted + (size_t)b1 * EPB;
    for (int i = lo1; i < hi1; i++) ebuf[dd1 + (i - lo1)] = sp[i];
  }
  cursor[t] = 0;
  __syncthreads();
  for (int i = t; i < M; i += 256) atomicAdd(&cursor[ebuf[i] & 255], 1);
  __syncthreads();
  int cnt = cursor[t];
  sa[t] = cnt;
  int* cu2 = sa; int* nx2 = sb;
  __syncthreads();
  for (int off = 1; off < 256; off <<= 1) {
    int v = cu2[t] + ((t >= off) ? cu2[t - off] : 0);
    __syncthreads();
    nx2[t] = v;
    __syncthreads();
    int* tmp = cu2; cu2 = nx2; nx2 = tmp;
  }
  int localrow = cu2[t] - cnt;
  int node = k * 256 + t;
  if (node < n) {
    rowstart[node] = s0 + localrow;
    norm[node] = rsqrtf((float)(cnt + 1));
  }
  if (k == NB - 1 && t == 255) rowstart[n] = E;
  cursor[t] = localrow;
  __syncthreads();
  for (int i = t; i < M; i += 256) {
    uint32_t pe = ebuf[i];
    int pos = atomicAdd(&cursor[pe & 255], 1);
    csr[s0 + pos] = (int)(pe >> 8);
  }
}

// MFMA gemm1: h0 = fp8(norm * (feat @ w1)). One wave per 16-node strip.
__global__ __launch_bounds__(256) void gemm1(const float* __restrict__ feat,
                                             const unsigned short* __restrict__ w1t,
                                             const float* __restrict__ norm,
                                             unsigned char* __restrict__ h0, int n) {
  int t = threadIdx.x;
  int wv = t >> 6, lane = t & 63;
  int strip = blockIdx.x * 4 + wv;
  if (strip * 16 >= n) return;
  int m = lane & 15, q = lane >> 4;
  bf16x8 Bf[4][4];
#pragma unroll
  for (int kc = 0; kc < 4; kc++)
#pragma unroll
    for (int ct = 0; ct < 4; ct++)
      Bf[kc][ct] = *(const bf16x8*)(w1t + (ct * 16 + m) * INDIM + kc * 32 + q * 8);
  const float* arow = feat + (size_t)(strip * 16 + m) * INDIM;
  bf16x8 Af[4];
#pragma unroll
  for (int kc = 0; kc < 4; kc++) {
    const float* pa = arow + kc * 32 + q * 8;
    bf16x8 a;
#pragma unroll
    for (int j = 0; j < 8; j++) a[j] = (short)f2bf(pa[j]);
    Af[kc] = a;
  }
  f32x4 acc[4] = {{0.f,0.f,0.f,0.f},{0.f,0.f,0.f,0.f},{0.f,0.f,0.f,0.f},{0.f,0.f,0.f,0.f}};
#pragma unroll
  for (int kc = 0; kc < 4; kc++)
#pragma unroll
    for (int ct = 0; ct < 4; ct++)
      acc[ct] = __builtin_amdgcn_mfma_f32_16x16x32_bf16(Af[kc], Bf[kc][ct], acc[ct], 0, 0, 0);
#pragma unroll
  for (int r = 0; r < 4; r++) {
    int row = strip * 16 + q * 4 + r;
    float nm = norm[row];
#pragma unroll
    for (int ct = 0; ct < 4; ct++)
      h0[(size_t)row * HID + ct * 16 + m] = f2fp8(acc[ct][r] * nm);
  }
}

// 4-node-per-wave CSR gather over fp8 rows, MODE 0 only:
// fused relu/dropout(ballot)/prescale -> fp8 out.
__global__ __launch_bounds__(256) void gather_k(const uint32_t* __restrict__ h8,
                                                uint32_t* __restrict__ outp,
                                                const int* __restrict__ rowstart,
                                                const int* __restrict__ csr,
                                                const float* __restrict__ norm,
                                                int n, uint32_t ka, uint32_t kb) {
  int wid = (int)((blockIdx.x * 256u + threadIdx.x) >> 6);
  int d0 = wid * 4;
  if (d0 >= n) return;
  int lane = threadIdx.x & 63;
  int g = lane >> 4, c4 = lane & 15;
  int g4 = g << 2;

  int rr = d0 + (lane < 4 ? lane : 4);
  if (rr > n) rr = n;
  int rsl = rowstart[rr];
  int r0[5];
#pragma unroll
  for (int i = 0; i < 5; ++i) r0[i] = __shfl(rsl, i);
  int L[4];
#pragma unroll
  for (int i = 0; i < 4; ++i) L[i] = r0[i + 1] - r0[i];

  int selfrow = d0 + g; if (selfrow >= n) selfrow = d0;
  uint32_t uself = h8[(size_t)selfrow * 16 + c4];

  int idx[4];
#pragma unroll
  for (int i = 0; i < 4; ++i) {
    int la = L[i] < 32 ? L[i] : 32;
    idx[i] = (lane < la) ? csr[r0[i] + lane] : 0;
  }

  uint32_t u[4][8];
#pragma unroll
  for (int i = 0; i < 4; ++i) {
#pragma unroll
    for (int t = 0; t < 8; ++t) {
      int s = __builtin_amdgcn_ds_bpermute(16 * t + g4, idx[i]);
      u[i][t] = (4 * t + g < L[i]) ? h8[(size_t)(uint32_t)s * 16 + c4] : 0u;
    }
  }

  f32x2 al[4], ah[4];
#pragma unroll
  for (int i = 0; i < 4; ++i) { al[i] = (f32x2){0.f, 0.f}; ah[i] = (f32x2){0.f, 0.f}; }
#pragma unroll
  for (int i = 0; i < 4; ++i) {
#pragma unroll
    for (int t = 0; t < 8; ++t) {
      al[i] += __builtin_amdgcn_cvt_pk_f32_fp8((int)u[i][t], false);
      ah[i] += __builtin_amdgcn_cvt_pk_f32_fp8((int)u[i][t], true);
    }
  }

#pragma unroll
  for (int i = 0; i < 4; ++i) {
    if (L[i] > 32) {
      for (int e0 = 32; e0 < L[i]; e0 += 4) {
        int e = e0 + g;
        uint32_t uu = 0u;
        if (e < L[i]) {
          int s = csr[r0[i] + e];
          uu = h8[(size_t)(uint32_t)s * 16 + c4];
        }
        al[i] += __builtin_amdgcn_cvt_pk_f32_fp8((int)uu, false);
        ah[i] += __builtin_amdgcn_cvt_pk_f32_fp8((int)uu, true);
      }
    }
  }

  f32x2 sl, sh, rl2, rh2;
  sl = (g & 1) ? al[0] : al[1];
  sh = (g & 1) ? ah[0] : ah[1];
  rl2.x = __shfl_xor(sl.x, 16); rl2.y = __shfl_xor(sl.y, 16);
  rh2.x = __shfl_xor(sh.x, 16); rh2.y = __shfl_xor(sh.y, 16);
  f32x2 fABl = ((g & 1) ? al[1] : al[0]) + rl2;
  f32x2 fABh = ((g & 1) ? ah[1] : ah[0]) + rh2;
  sl = (g & 1) ? al[2] : al[3];
  sh = (g & 1) ? ah[2] : ah[3];
  rl2.x = __shfl_xor(sl.x, 16); rl2.y = __shfl_xor(sl.y, 16);
  rh2.x = __shfl_xor(sh.x, 16); rh2.y = __shfl_xor(sh.y, 16);
  f32x2 fCDl = ((g & 1) ? al[3] : al[2]) + rl2;
  f32x2 fCDh = ((g & 1) ? ah[3] : ah[2]) + rh2;
  sl = (g & 2) ? fABl : fCDl;
  sh = (g & 2) ? fABh : fCDh;
  rl2.x = __shfl_xor(sl.x, 32); rl2.y = __shfl_xor(sl.y, 32);
  rh2.x = __shfl_xor(sh.x, 32); rh2.y = __shfl_xor(sh.y, 32);
  f32x2 tl = ((g & 2) ? fCDl : fABl) + rl2;
  f32x2 th = ((g & 2) ? fCDh : fABh) + rh2;

  tl += __builtin_amdgcn_cvt_pk_f32_fp8((int)uself, false);
  th += __builtin_amdgcn_cvt_pk_f32_fp8((int)uself, true);

  int d = d0 + g;
  uint32_t jb = (uint32_t)d0 * 64u + (uint32_t)lane;
  float u0 = tf_uniform(ka, kb, jb);
  float u1 = tf_uniform(ka, kb, jb + 64u);
  float u2 = tf_uniform(ka, kb, jb + 128u);
  float u3 = tf_uniform(ka, kb, jb + 192u);
  unsigned long long kp0 = __ballot(u0 < 0.5f);
  unsigned long long kp1 = __ballot(u1 < 0.5f);
  unsigned long long kp2 = __ballot(u2 < 0.5f);
  unsigned long long kp3 = __ballot(u3 < 0.5f);
  unsigned long long keep = (g & 2) ? ((g & 1) ? kp3 : kp2)
                                    : ((g & 1) ? kp1 : kp0);
  uint32_t kb4 = (uint32_t)(keep >> (4 * c4)) & 15u;
  float nm = norm[d < n ? d : d0];
  float v0 = fmaxf(tl.x * nm, 0.f), v1 = fmaxf(tl.y * nm, 0.f);
  float v2 = fmaxf(th.x * nm, 0.f), v3 = fmaxf(th.y * nm, 0.f);
  float s2 = 2.f * nm;
  v0 = (kb4 & 1u) ? v0 * s2 : 0.f;
  v1 = (kb4 & 2u) ? v1 * s2 : 0.f;
  v2 = (kb4 & 4u) ? v2 * s2 : 0.f;
  v3 = (kb4 & 8u) ? v3 * s2 : 0.f;
  if (d < n) {
    int o = __builtin_amdgcn_cvt_pk_fp8_f32(v0, v1, 0, false);
    o = __builtin_amdgcn_cvt_pk_fp8_f32(v2, v3, o, true);
    outp[(size_t)d * 16 + c4] = (uint32_t)o;
  }
}

// Fused gather<1> + gemm2: block = one 16-node strip (4 waves x 4 nodes).
// Phase 1 (all waves): raw CSR gather -> bf16 strip tile in LDS (padded).
// Phase 2 (ALL 4 waves): wave wv computes output-column quadrant ct=wv
// (2 MFMAs + 4 tf_uniform/lane, vs 8 MFMAs + 16 tf_uniform on one wave
// previously) -> h2 slice + colsum. Removes the single-wave serial tail.
__global__ __launch_bounds__(256) void gather2gemm2_k(
    const uint32_t* __restrict__ h8, const int* __restrict__ rowstart,
    const int* __restrict__ csr, const float* __restrict__ norm,
    const unsigned short* __restrict__ w2t, unsigned short* __restrict__ h2,
    float* __restrict__ colsumR, int n, uint32_t ka, uint32_t kb) {
  __shared__ unsigned short abuf[16][72];   // +8 pad breaks bank conflicts
  int t = threadIdx.x;
  int wv = t >> 6, lane = t & 63;
  int node0 = blockIdx.x * 16;
  int d0 = node0 + wv * 4;
  int g = lane >> 4, c4 = lane & 15;
  int g4 = g << 2;
  int lrow = (wv << 2) + g;

  if (d0 < n) {
    int rr = d0 + (lane < 4 ? lane : 4);
    if (rr > n) rr = n;
    int rsl = rowstart[rr];
    int r0[5];
#pragma unroll
    for (int i = 0; i < 5; ++i) r0[i] = __shfl(rsl, i);
    int L[4];
#pragma unroll
    for (int i = 0; i < 4; ++i) L[i] = r0[i + 1] - r0[i];

    int selfrow = d0 + g; if (selfrow >= n) selfrow = d0;
    uint32_t uself = h8[(size_t)selfrow * 16 + c4];

    int idx[4];
#pragma unroll
    for (int i = 0; i < 4; ++i) {
      int la = L[i] < 32 ? L[i] : 32;
      idx[i] = (lane < la) ? csr[r0[i] + lane] : 0;
    }

    uint32_t u[4][8];
#pragma unroll
    for (int i = 0; i < 4; ++i) {
#pragma unroll
      for (int tt = 0; tt < 8; ++tt) {
        int s = __builtin_amdgcn_ds_bpermute(16 * tt + g4, idx[i]);
        u[i][tt] = (4 * tt + g < L[i]) ? h8[(size_t)(uint32_t)s * 16 + c4] : 0u;
      }
    }

    f32x2 al[4], ah[4];
#pragma unroll
    for (int i = 0; i < 4; ++i) { al[i] = (f32x2){0.f, 0.f}; ah[i] = (f32x2){0.f, 0.f}; }
#pragma unroll
    for (int i = 0; i < 4; ++i) {
#pragma unroll
      for (int tt = 0; tt < 8; ++tt) {
        al[i] += __builtin_amdgcn_cvt_pk_f32_fp8((int)u[i][tt], false);
        ah[i] += __builtin_amdgcn_cvt_pk_f32_fp8((int)u[i][tt], true);
      }
    }

#pragma unroll
    for (int i = 0; i < 4; ++i) {
      if (L[i] > 32) {
        for (int e0 = 32; e0 < L[i]; e0 += 4) {
          int e = e0 + g;
          uint32_t uu = 0u;
          if (e < L[i]) {
            int s = csr[r0[i] + e];
            uu = h8[(size_t)(uint32_t)s * 16 + c4];
          }
          al[i] += __builtin_amdgcn_cvt_pk_f32_fp8((int)uu, false);
          ah[i] += __builtin_amdgcn_cvt_pk_f32_fp8((int)uu, true);
        }
      }
    }

    f32x2 sl, sh, rl2, rh2;
    sl = (g & 1) ? al[0] : al[1];
    sh = (g & 1) ? ah[0] : ah[1];
    rl2.x = __shfl_xor(sl.x, 16); rl2.y = __shfl_xor(sl.y, 16);
    rh2.x = __shfl_xor(sh.x, 16); rh2.y = __shfl_xor(sh.y, 16);
    f32x2 fABl = ((g & 1) ? al[1] : al[0]) + rl2;
    f32x2 fABh = ((g & 1) ? ah[1] : ah[0]) + rh2;
    sl = (g & 1) ? al[2] : al[3];
    sh = (g & 1) ? ah[2] : ah[3];
    rl2.x = __shfl_xor(sl.x, 16); rl2.y = __shfl_xor(sl.y, 16);
    rh2.x = __shfl_xor(sh.x, 16); rh2.y = __shfl_xor(sh.y, 16);
    f32x2 fCDl = ((g & 1) ? al[3] : al[2]) + rl2;
    f32x2 fCDh = ((g & 1) ? ah[3] : ah[2]) + rh2;
    sl = (g & 2) ? fABl : fCDl;
    sh = (g & 2) ? fABh : fCDh;
    rl2.x = __shfl_xor(sl.x, 32); rl2.y = __shfl_xor(sl.y, 32);
    rh2.x = __shfl_xor(sh.x, 32); rh2.y = __shfl_xor(sh.y, 32);
    f32x2 tl = ((g & 2) ? fCDl : fABl) + rl2;
    f32x2 th = ((g & 2) ? fCDh : fABh) + rh2;

    tl += __builtin_amdgcn_cvt_pk_f32_fp8((int)uself, false);
    th += __builtin_amdgcn_cvt_pk_f32_fp8((int)uself, true);

    uint2 w;
    w.x = (uint32_t)f2bf(tl.x) | ((uint32_t)f2bf(tl.y) << 16);
    w.y = (uint32_t)f2bf(th.x) | ((uint32_t)f2bf(th.y) << 16);
    if (d0 + g >= n) { w.x = 0u; w.y = 0u; }
    *(uint2*)&abuf[lrow][4 * c4] = w;
  } else {
    uint2 z; z.x = 0u; z.y = 0u;
    *(uint2*)&abuf[lrow][4 * c4] = z;
  }
  __syncthreads();
  if (node0 >= n) return;

  // ---- gemm2 phase: wave wv computes column quadrant ct = wv ----
  int m = lane & 15, q = lane >> 4;
  f32x4 acc = {0.f, 0.f, 0.f, 0.f};
#pragma unroll
  for (int kc = 0; kc < 2; kc++) {
    bf16x8 Af = *(const bf16x8*)&abuf[m][kc * 32 + q * 8];
    bf16x8 Bf = *(const bf16x8*)(w2t + (wv * 16 + m) * HID + kc * 32 + q * 8);
    acc = __builtin_amdgcn_mfma_f32_16x16x32_bf16(Af, Bf, acc, 0, 0, 0);
  }
  float cs = 0.f;
  int col = wv * 16 + m;
#pragma unroll
  for (int r = 0; r < 4; r++) {
    int row = node0 + q * 4 + r;
    if (row < n) {
      float nm = norm[row];
      float v = fmaxf(acc[r] * nm, 0.f);
      float uu = tf_uniform(ka, kb, (uint32_t)row * 64u + (uint32_t)col);
      v = (uu < 0.5f) ? v * 2.f : 0.f;
      h2[(size_t)row * HID + col] = f2bf(v);
      cs += v;
    }
  }
  cs += __shfl_xor(cs, 16);
  cs += __shfl_xor(cs, 32);
  if (q == 0)
    atomicAdd(&colsumR[(blockIdx.x & (CSREP - 1)) * HID + col], cs);
}

__global__ __launch_bounds__(128) void final_k(const uint32_t* __restrict__ h2u,
                                               const float* __restrict__ colsumR,
                                               const float* __restrict__ conv_w,
                                               const float* __restrict__ conv_b,
                                               const float* __restrict__ ref_radius,
                                               float* __restrict__ out, int n) {
  __shared__ float rows[128 * 67];
  __shared__ float omean[124];
  __shared__ float cm[HID];
  int t = threadIdx.x;
  int node0 = blockIdx.x * 128;
  if (t < HID) {
    float s = 0.f;
#pragma unroll
    for (int r = 0; r < CSREP; r++) s += colsumR[r * HID + t];
    cm[t] = s * (1.0f / (float)n);
  }
  for (int idx = t; idx < 128 * 32; idx += 128) {
    int r = idx >> 5, cpi = idx & 31;
    int node = node0 + r;
    uint32_t u = (node < n) ? h2u[(size_t)node * 32 + cpi] : 0u;
    rows[r * 67 + 2 * cpi] = bf2f_lo(u);
    rows[r * 67 + 2 * cpi + 1] = bf2f_hi(u);
  }
  __syncthreads();
  if (t < 124) {
    int o = t / 62, i = t % 62;
    omean[t] = conv_b[o] + conv_w[o * 3] * cm[i] + conv_w[o * 3 + 1] * cm[i + 1] +
               conv_w[o * 3 + 2] * cm[i + 2];
  }
  __syncthreads();
  int node = node0 + t;
  if (node < n) {
    float r0[HID];
#pragma unroll
    for (int k = 0; k < HID; k++) r0[k] = rows[t * 67 + k];
    float w00 = conv_w[0], w01 = conv_w[1], w02 = conv_w[2];
    float w10 = conv_w[3], w11 = conv_w[4], w12 = conv_w[5];
    float b0 = conv_b[0], b1 = conv_b[1];
    float acc = 0.f;
#pragma unroll
    for (int i = 0; i < 62; i++) {
      float y0 = b0 + w00 * r0[i] + w01 * r0[i + 1] + w02 * r0[i + 2];
      float d0 = y0 - omean[i] + 1e-6f;
      acc += d0 * d0;
      float y1 = b1 + w10 * r0[i] + w11 * r0[i + 1] + w12 * r0[i + 2];
      float d1 = y1 - omean[62 + i] + 1e-6f;
      acc += d1 * d1;
    }
    float radius = sqrtf(acc);
    float dis = fminf(fmaxf(radius - ref_radius[0], 1e-4f), 1.f - 1e-4f);
    out[node] = dis;
  }
  if (blockIdx.x == 0 && t == 0) out[n] = ref_radius[0];
}

extern "C" void kernel_launch(void* const* d_in, const int* in_sizes, int n_in,
                              void* d_out, int out_size, void* d_ws, size_t ws_size,
                              hipStream_t stream) {
  const float* feat = (const float*)d_in[0];
  const float* w1 = (const float*)d_in[1];
  const float* w2 = (const float*)d_in[2];
  const float* conv_w = (const float*)d_in[3];
  const float* conv_b = (const float*)d_in[4];
  const float* ref_radius = (const float*)d_in[5];
  const int* src = (const int*)d_in[6];
  const int* dst = (const int*)d_in[7];
  int n = in_sizes[0] / INDIM;
  int E = in_sizes[6];
  float* out = (float*)d_out;

  int NB = (n + 255) >> 8;                 // 391 buckets of 256 nodes
  int EPB = (E + NBLK - 1) / NBLK;         // 3125 edges per binsort block

  char* p = (char*)d_ws;
  auto carve = [&](size_t bytes) { void* r = (void*)p; p += (bytes + 255) & ~(size_t)255; return r; };
  float* norm = (float*)carve((size_t)n * 4);
  float* colsumR = (float*)carve((size_t)CSREP * HID * 4);
  int* rowstart = (int*)carve(((size_t)n + 1) * 4);
  int* blockoff2 = (int*)carve((size_t)(NB + 1) * NBLK * 4);   // [bucket][block]
  uint32_t* sorted = (uint32_t*)carve((size_t)E * 4);
  int* csr = (int*)carve((size_t)E * 4);
  unsigned short* w1t = (unsigned short*)carve((size_t)INDIM * HID * 2);
  unsigned short* w2t = (unsigned short*)carve((size_t)HID * HID * 2);
  unsigned char* H0f8 = (unsigned char*)carve((size_t)n * HID);
  unsigned char* Tf8 = (unsigned char*)carve((size_t)n * HID);
  unsigned short* H2bf = (unsigned short*)carve((size_t)n * HID * 2);

  uint32_t k1a, k1b, k2a, k2b;
  tf2x32(0u, 42u, 0u, 0u, k1a, k1b);
  tf2x32(0u, 42u, 0u, 1u, k2a, k2b);

  int gatherB = (n + 15) / 16;             // wave per 4 nodes, 4 waves per block
  int stripB = ((n + 15) / 16 + 3) / 4;    // wave per 16-node strip

  binsort_k<<<NBLK, 256, 0, stream>>>(src, dst, sorted, blockoff2, w1, w2, w1t, w2t, colsumR, E, EPB, NB);
  csrbuild_k<<<NB, 256, 0, stream>>>(sorted, blockoff2, rowstart, csr, norm, NB, n, E, EPB);
  gemm1<<<stripB, 256, 0, stream>>>(feat, w1t, norm, H0f8, n);
  gather_k<<<gatherB, 256, 0, stream>>>((const uint32_t*)H0f8, (uint32_t*)Tf8, rowstart, csr, norm, n, k1a, k1b);
  gather2gemm2_k<<<gatherB, 256, 0, stream>>>((const uint32_t*)Tf8, rowstart, csr, norm, w2t, H2bf, colsumR, n, k2a, k2b);
  final_k<<<(n + 127) / 128, 128, 0, stream>>>((const uint32_t*)H2bf, colsumR, conv_w, conv_b, ref_radius, out, n);
}